// Round 7
// baseline (403.781 us; speedup 1.0000x reference)
//
#include <hip/hip_runtime.h>
#include <math.h>

// VQ-VAE EMA vector quantizer for MI355X (gfx950).
// Argmin bit-replicates the numpy-f32 reference: dists = (sum(x*x) - (2x)@emb.T) + sum(e*e),
// numpy pairwise row-sums, BLAS sequential-FMA dot, first-occurrence argmin.
// dw/counts via counting-sort segmented reduction (no f32 global atomics).
// Round 7: X kept in LDS column-major (xs[d][t]) as an explicit register extension —
// three rounds proved the compiler pins k_scores at 52 VGPRs and spills X to scratch
// (WRITE_SIZE 105MB vs 35MB ideal). Per-thread reg demand is now ~30. Bank pattern
// (d*128+t), fixed d per wave -> t mod 32 -> 2 lanes/bank = conflict-free.
#define NROWS 131072          // 32*4096
#define DIM 64
#define NCODE 512
#define BLK 128               // threads per k_scores block (LDS: 64*128*4 = 32 KB)

// d_out float offsets (outputs concatenated flat, all float32-viewed)
#define OUT_ZQ    0
#define OUT_LOSS  8388608
#define OUT_CODES 8388609
#define OUT_ECS   8519681
#define OUT_EMAW  8520193
#define OUT_EMB   8552961

// workspace byte offsets
#define WS_LOSS    0         // double
#define WS_N       8         // float
#define WS_COUNTS  16        // int[512]
#define WS_OFFSETS 2064      // int[512]
#define WS_CURSOR  4112      // int[512]
#define WS_CSUM    6160      // float[512]
#define WS_CODESI  8208      // int[131072]
#define WS_BUCKET  532496    // int[131072]
#define WS_DW      1056784   // float[32768]
#define WS_BYTES   1187856
#define WS_ZERO_BYTES 2064   // loss + n + counts

// reference scalar constants
#define DECAY_C ((float)0.9)
#define OMD_C   ((float)(1.0 - 0.9))
#define EPS_C   ((float)1e-5)

// repetition macros (all indices literal constants)
#define R4(M, b)  M(b) M((b) + 1) M((b) + 2) M((b) + 3)
#define R16(M, b) R4(M, b) R4(M, (b) + 4) R4(M, (b) + 8) R4(M, (b) + 12)

// numpy pairwise sum (scalar unroll-8 path, n=64) of v[d]*v[d], f32, no contraction.
__device__ __forceinline__ float np_pairwise64_sq(const float* v) {
    float r[8];
#pragma unroll
    for (int j = 0; j < 8; ++j) r[j] = __fmul_rn(v[j], v[j]);
#pragma unroll
    for (int b = 1; b < 8; ++b) {
#pragma unroll
        for (int j = 0; j < 8; ++j)
            r[j] = __fadd_rn(r[j], __fmul_rn(v[8 * b + j], v[8 * b + j]));
    }
    return __fadd_rn(__fadd_rn(__fadd_rn(r[0], r[1]), __fadd_rn(r[2], r[3])),
                     __fadd_rn(__fadd_rn(r[4], r[5]), __fadd_rn(r[6], r[7])));
}

// ---- csum[k] = np.sum(emb[k]*emb[k]) with numpy pairwise bits ----
__global__ void k_csum(const float* __restrict__ emb, float* __restrict__ csum) {
    int k = blockIdx.x * blockDim.x + threadIdx.x;
    if (k >= NCODE) return;
    float e[DIM];
#pragma unroll
    for (int d = 0; d < DIM; d += 4) {
        float4 v = *reinterpret_cast<const float4*>(emb + (size_t)k * DIM + d);
        e[d] = v.x; e[d + 1] = v.y; e[d + 2] = v.z; e[d + 3] = v.w;
    }
    csum[k] = np_pairwise64_sq(e);
}

// ---- fused: argmin + codes + z_q + loss + LDS histogram; X lives in LDS ----
__global__ __launch_bounds__(BLK) void k_scores(
        const float* __restrict__ ze, const float* __restrict__ emb,
        const float* __restrict__ csum, float* __restrict__ out,
        int* __restrict__ codes_i, int* __restrict__ counts,
        double* __restrict__ lossAcc) {
    __shared__ float xs[DIM][BLK];   // xs[d][t] = 2*x_d for thread t's row
    __shared__ int h[NCODE];
    __shared__ double ls[BLK / 64];
    int t = threadIdx.x;
    for (int i = t; i < NCODE; i += BLK) h[i] = 0;
    __syncthreads();

    int row = blockIdx.x * BLK + t;
    const float* x = ze + (size_t)row * DIM;

    // load row, double it, stash column-major in LDS; numpy pairwise-square on the fly
    float r0, r1, r2, r3, r4, r5, r6, r7;
    {   // block b = 0 (d = 0..7): initialize r[j]
        float4 va = *reinterpret_cast<const float4*>(x + 0);
        float4 vb = *reinterpret_cast<const float4*>(x + 4);
        float d0 = __fadd_rn(va.x, va.x), d1 = __fadd_rn(va.y, va.y);
        float d2 = __fadd_rn(va.z, va.z), d3 = __fadd_rn(va.w, va.w);
        float d4 = __fadd_rn(vb.x, vb.x), d5 = __fadd_rn(vb.y, vb.y);
        float d6 = __fadd_rn(vb.z, vb.z), d7 = __fadd_rn(vb.w, vb.w);
        xs[0][t] = d0; xs[1][t] = d1; xs[2][t] = d2; xs[3][t] = d3;
        xs[4][t] = d4; xs[5][t] = d5; xs[6][t] = d6; xs[7][t] = d7;
        r0 = __fmul_rn(d0, d0); r1 = __fmul_rn(d1, d1);
        r2 = __fmul_rn(d2, d2); r3 = __fmul_rn(d3, d3);
        r4 = __fmul_rn(d4, d4); r5 = __fmul_rn(d5, d5);
        r6 = __fmul_rn(d6, d6); r7 = __fmul_rn(d7, d7);
    }
#define LD8(b) { \
        float4 va = *reinterpret_cast<const float4*>(x + 8 * (b)); \
        float4 vb = *reinterpret_cast<const float4*>(x + 8 * (b) + 4); \
        float d0 = __fadd_rn(va.x, va.x), d1 = __fadd_rn(va.y, va.y); \
        float d2 = __fadd_rn(va.z, va.z), d3 = __fadd_rn(va.w, va.w); \
        float d4 = __fadd_rn(vb.x, vb.x), d5 = __fadd_rn(vb.y, vb.y); \
        float d6 = __fadd_rn(vb.z, vb.z), d7 = __fadd_rn(vb.w, vb.w); \
        xs[8 * (b) + 0][t] = d0; xs[8 * (b) + 1][t] = d1; \
        xs[8 * (b) + 2][t] = d2; xs[8 * (b) + 3][t] = d3; \
        xs[8 * (b) + 4][t] = d4; xs[8 * (b) + 5][t] = d5; \
        xs[8 * (b) + 6][t] = d6; xs[8 * (b) + 7][t] = d7; \
        r0 = __fadd_rn(r0, __fmul_rn(d0, d0)); r1 = __fadd_rn(r1, __fmul_rn(d1, d1)); \
        r2 = __fadd_rn(r2, __fmul_rn(d2, d2)); r3 = __fadd_rn(r3, __fmul_rn(d3, d3)); \
        r4 = __fadd_rn(r4, __fmul_rn(d4, d4)); r5 = __fadd_rn(r5, __fmul_rn(d5, d5)); \
        r6 = __fadd_rn(r6, __fmul_rn(d6, d6)); r7 = __fadd_rn(r7, __fmul_rn(d7, d7)); }
    LD8(1) LD8(2) LD8(3) LD8(4) LD8(5) LD8(6) LD8(7)
    // A = sum(x^2) = 0.25 * sum((2x)^2), numpy pairwise combine, bit-exact
    float A = __fmul_rn(0.25f,
        __fadd_rn(__fadd_rn(__fadd_rn(r0, r1), __fadd_rn(r2, r3)),
                  __fadd_rn(__fadd_rn(r4, r5), __fadd_rn(r6, r7))));

    float m1 = 3.4e38f;
    int i1 = 0;
#define FMAD(dd) { const float xv = xs[dd][t]; \
        a0 = __builtin_fmaf(xv, e[(dd)      ], a0); \
        a1 = __builtin_fmaf(xv, e[(dd) +  64], a1); \
        a2 = __builtin_fmaf(xv, e[(dd) + 128], a2); \
        a3 = __builtin_fmaf(xv, e[(dd) + 192], a3); \
        a4 = __builtin_fmaf(xv, e[(dd) + 256], a4); \
        a5 = __builtin_fmaf(xv, e[(dd) + 320], a5); \
        a6 = __builtin_fmaf(xv, e[(dd) + 384], a6); \
        a7 = __builtin_fmaf(xv, e[(dd) + 448], a7); }
    for (int k = 0; k < NCODE; k += 8) {
        const float* e = emb + (size_t)k * DIM;     // wave-uniform -> scalar loads
        float a0 = 0.f, a1 = 0.f, a2 = 0.f, a3 = 0.f;
        float a4 = 0.f, a5 = 0.f, a6 = 0.f, a7 = 0.f;
        R16(FMAD, 0) R16(FMAD, 16) R16(FMAD, 32) R16(FMAD, 48)   // d ascending, BLAS chain
        float t0 = __fadd_rn(__fsub_rn(A, a0), csum[k + 0]);
        float t1 = __fadd_rn(__fsub_rn(A, a1), csum[k + 1]);
        float t2 = __fadd_rn(__fsub_rn(A, a2), csum[k + 2]);
        float t3 = __fadd_rn(__fsub_rn(A, a3), csum[k + 3]);
        float t4 = __fadd_rn(__fsub_rn(A, a4), csum[k + 4]);
        float t5 = __fadd_rn(__fsub_rn(A, a5), csum[k + 5]);
        float t6 = __fadd_rn(__fsub_rn(A, a6), csum[k + 6]);
        float t7 = __fadd_rn(__fsub_rn(A, a7), csum[k + 7]);
        if (t0 < m1) { m1 = t0; i1 = k; }           // strict < keeps first occurrence
        if (t1 < m1) { m1 = t1; i1 = k + 1; }
        if (t2 < m1) { m1 = t2; i1 = k + 2; }
        if (t3 < m1) { m1 = t3; i1 = k + 3; }
        if (t4 < m1) { m1 = t4; i1 = k + 4; }
        if (t5 < m1) { m1 = t5; i1 = k + 5; }
        if (t6 < m1) { m1 = t6; i1 = k + 6; }
        if (t7 < m1) { m1 = t7; i1 = k + 7; }
    }
    out[OUT_CODES + row] = (float)i1;
    codes_i[row] = i1;
    atomicAdd(&h[i1], 1);                           // LDS atomic

    // z_q = x + (e - x), loss accumulation; x recovered exactly as 0.5*(2x)
    const float* e1 = emb + (size_t)i1 * DIM;
    float* zq = out + OUT_ZQ + (size_t)row * DIM;
    double lsum = 0.0;
#define ZQ4(q) { \
        float4 ev = *reinterpret_cast<const float4*>(e1 + 4 * (q)); \
        float xa = __fmul_rn(0.5f, xs[4 * (q) + 0][t]); \
        float xb = __fmul_rn(0.5f, xs[4 * (q) + 1][t]); \
        float xc = __fmul_rn(0.5f, xs[4 * (q) + 2][t]); \
        float xd = __fmul_rn(0.5f, xs[4 * (q) + 3][t]); \
        float ta = __fsub_rn(ev.x, xa); \
        float tb = __fsub_rn(ev.y, xb); \
        float tc = __fsub_rn(ev.z, xc); \
        float td = __fsub_rn(ev.w, xd); \
        float4 o; \
        o.x = __fadd_rn(xa, ta); \
        o.y = __fadd_rn(xb, tb); \
        o.z = __fadd_rn(xc, tc); \
        o.w = __fadd_rn(xd, td); \
        *reinterpret_cast<float4*>(zq + 4 * (q)) = o; \
        lsum += (double)ta * ta + (double)tb * tb + (double)tc * tc + (double)td * td; }
    R16(ZQ4, 0)

    for (int off = 32; off; off >>= 1) lsum += __shfl_down(lsum, off);
    int wid = t >> 6;
    if ((t & 63) == 0) ls[wid] = lsum;
    __syncthreads();                                // also orders LDS histogram
    if (t == 0) atomicAdd(lossAcc, ls[0] + ls[1]);
    for (int k = t; k < NCODE; k += BLK) {
        int c = h[k];
        if (c) atomicAdd(&counts[k], c);            // int global atomic, aggregated
    }
}

// ---- one block: exclusive scan of counts -> offsets/cursor; new_ecs + n ----
__global__ __launch_bounds__(512) void k_scan(
        const int* __restrict__ counts, int* __restrict__ offsets, int* __restrict__ cursor,
        const float* __restrict__ ecs_in, float* __restrict__ out, float* __restrict__ n_out) {
    __shared__ int sa[NCODE], sb[NCODE];
    __shared__ float red[NCODE];
    int k = threadIdx.x;
    int c = counts[k];
    sa[k] = c;
    float v = __fadd_rn(__fmul_rn(ecs_in[k], DECAY_C), __fmul_rn((float)c, OMD_C));
    out[OUT_ECS + k] = v;
    red[k] = v;
    __syncthreads();
    int* src = sa;
    int* dst = sb;
    for (int off = 1; off < NCODE; off <<= 1) {
        dst[k] = (k >= off) ? src[k - off] + src[k] : src[k];
        __syncthreads();
        int* tp = src; src = dst; dst = tp;
    }
    offsets[k] = src[k] - c;
    cursor[k]  = src[k] - c;
    for (int s = NCODE / 2; s > 0; s >>= 1) {
        if (k < s) red[k] += red[k + s];
        __syncthreads();
    }
    if (k == 0) n_out[0] = red[0];
}

// ---- scatter rows into code buckets ----
__global__ __launch_bounds__(256) void k_scatter(
        const int* __restrict__ codes_i, int* __restrict__ cursor, int* __restrict__ bucket) {
    int row = blockIdx.x * 256 + threadIdx.x;
    int c = codes_i[row];
    int pos = atomicAdd(&cursor[c], 1);
    bucket[pos] = row;
}

// ---- per-code segmented sum: dw[k][d] = sum of ze rows in bucket k (no atomics) ----
__global__ __launch_bounds__(256) void k_dw(
        const float* __restrict__ ze, const int* __restrict__ bucket,
        const int* __restrict__ offsets, const int* __restrict__ counts,
        float* __restrict__ dw) {
    __shared__ float p[4][DIM];
    int k = blockIdx.x;
    int w = threadIdx.x >> 6;       // wave 0..3
    int d = threadIdx.x & 63;
    int s = offsets[k];
    int n = counts[k];
    float acc0 = 0.f, acc1 = 0.f;
    int i = w;
    for (; i + 4 < n; i += 8) {     // 2 gathers in flight per wave
        int ra = bucket[s + i];
        int rb = bucket[s + i + 4];
        acc0 += ze[(size_t)ra * DIM + d];
        acc1 += ze[(size_t)rb * DIM + d];
    }
    if (i < n) acc0 += ze[(size_t)bucket[s + i] * DIM + d];
    p[w][d] = acc0 + acc1;
    __syncthreads();
    if (w == 0) dw[k * DIM + d] = (p[0][d] + p[1][d]) + (p[2][d] + p[3][d]);
}

// ---- new_ema_w, new_emb, loss ----
__global__ __launch_bounds__(256) void k_final(
        const float* __restrict__ ema_w, const float* __restrict__ dw,
        const float* __restrict__ n_ptr, const double* __restrict__ lossAcc,
        float* __restrict__ out) {
    int i = blockIdx.x * blockDim.x + threadIdx.x;
    if (i >= NCODE * DIM) return;
    int k = i >> 6;
    float w = __fadd_rn(__fmul_rn(ema_w[i], DECAY_C), __fmul_rn(dw[i], OMD_C));
    out[OUT_EMAW + i] = w;
    float n = n_ptr[0];
    float necs = out[OUT_ECS + k];
    float cs = (necs + EPS_C) / (n + (float)NCODE * EPS_C) * n;
    out[OUT_EMB + i] = w / (cs + EPS_C);
    if (i == 0) out[OUT_LOSS] = (float)(0.1 * (lossAcc[0] / (double)((size_t)NROWS * DIM)));
}

extern "C" void kernel_launch(void* const* d_in, const int* in_sizes, int n_in,
                              void* d_out, int out_size, void* d_ws, size_t ws_size,
                              hipStream_t stream) {
    const float* ze   = (const float*)d_in[0];
    const float* emb  = (const float*)d_in[1];
    const float* ecs  = (const float*)d_in[2];
    const float* emaw = (const float*)d_in[3];
    float* out = (float*)d_out;
    char* ws = (char*)d_ws;
    double* lossAcc = (double*)(ws + WS_LOSS);
    float*  n_out   = (float*)(ws + WS_N);
    int*    counts  = (int*)(ws + WS_COUNTS);
    int*    offsets = (int*)(ws + WS_OFFSETS);
    int*    cursor  = (int*)(ws + WS_CURSOR);
    float*  csum    = (float*)(ws + WS_CSUM);
    int*    codes_i = (int*)(ws + WS_CODESI);
    int*    bucket  = (int*)(ws + WS_BUCKET);
    float*  dw      = (float*)(ws + WS_DW);

    hipMemsetAsync(d_ws, 0, WS_ZERO_BYTES, stream);
    hipLaunchKernelGGL(k_csum, dim3(2), dim3(256), 0, stream, emb, csum);
    hipLaunchKernelGGL(k_scores, dim3(NROWS / BLK), dim3(BLK), 0, stream,
                       ze, emb, csum, out, codes_i, counts, lossAcc);
    hipLaunchKernelGGL(k_scan, dim3(1), dim3(512), 0, stream,
                       counts, offsets, cursor, ecs, out, n_out);
    hipLaunchKernelGGL(k_scatter, dim3(NROWS / 256), dim3(256), 0, stream,
                       codes_i, cursor, bucket);
    hipLaunchKernelGGL(k_dw, dim3(NCODE), dim3(256), 0, stream,
                       ze, bucket, offsets, counts, dw);
    hipLaunchKernelGGL(k_final, dim3(NCODE * DIM / 256), dim3(256), 0, stream,
                       emaw, dw, n_out, lossAcc, out);
}

// Round 8
// 241.248 us; speedup vs baseline: 1.6737x; 1.6737x over previous
//
#include <hip/hip_runtime.h>
#include <math.h>

// VQ-VAE EMA vector quantizer for MI355X (gfx950).
// Argmin bit-replicates the numpy-f32 reference: dists = (sum(x*x) - (2x)@emb.T) + sum(e*e),
// numpy pairwise row-sums, BLAS sequential-FMA dot, first-occurrence argmin.
// dw/counts via counting-sort segmented reduction (no f32 global atomics).
// Round 8: split-K k_scores — 256 threads / 128 rows, halves score codes 0-255 / 256-511
// sharing one xs[64][128] (twin writes identical bits), argmin merged via LDS.
// Doubles occupancy (8 -> 16 waves/CU) to hide scalar-load latency. readfirstlane
// keeps the e-pointer wave-uniform so emb loads stay on the s_load path.
#define NROWS 131072          // 32*4096
#define DIM 64
#define NCODE 512

// d_out float offsets (outputs concatenated flat, all float32-viewed)
#define OUT_ZQ    0
#define OUT_LOSS  8388608
#define OUT_CODES 8388609
#define OUT_ECS   8519681
#define OUT_EMAW  8520193
#define OUT_EMB   8552961

// workspace byte offsets
#define WS_LOSS    0         // double
#define WS_N       8         // float
#define WS_COUNTS  16        // int[512]
#define WS_OFFSETS 2064      // int[512]
#define WS_CURSOR  4112      // int[512]
#define WS_CSUM    6160      // float[512]
#define WS_CODESI  8208      // int[131072]; retired after k_scatter, reused as dw4
#define WS_DW4     8208      // float[4*512*64] = 512 KB, aliases codes_i (safe: k_dw after k_scatter)
#define WS_BUCKET  532496    // int[131072]
#define WS_BYTES   1056784
#define WS_ZERO_BYTES 2064   // loss + n + counts

// reference scalar constants
#define DECAY_C ((float)0.9)
#define OMD_C   ((float)(1.0 - 0.9))
#define EPS_C   ((float)1e-5)

// repetition macros (all indices literal constants)
#define R4(M, b)  M(b) M((b) + 1) M((b) + 2) M((b) + 3)
#define R16(M, b) R4(M, b) R4(M, (b) + 4) R4(M, (b) + 8) R4(M, (b) + 12)

// numpy pairwise sum (scalar unroll-8 path, n=64) of v[d]*v[d], f32, no contraction.
__device__ __forceinline__ float np_pairwise64_sq(const float* v) {
    float r[8];
#pragma unroll
    for (int j = 0; j < 8; ++j) r[j] = __fmul_rn(v[j], v[j]);
#pragma unroll
    for (int b = 1; b < 8; ++b) {
#pragma unroll
        for (int j = 0; j < 8; ++j)
            r[j] = __fadd_rn(r[j], __fmul_rn(v[8 * b + j], v[8 * b + j]));
    }
    return __fadd_rn(__fadd_rn(__fadd_rn(r[0], r[1]), __fadd_rn(r[2], r[3])),
                     __fadd_rn(__fadd_rn(r[4], r[5]), __fadd_rn(r[6], r[7])));
}

// ---- csum[k] = np.sum(emb[k]*emb[k]) with numpy pairwise bits ----
__global__ void k_csum(const float* __restrict__ emb, float* __restrict__ csum) {
    int k = blockIdx.x * blockDim.x + threadIdx.x;
    if (k >= NCODE) return;
    float e[DIM];
#pragma unroll
    for (int d = 0; d < DIM; d += 4) {
        float4 v = *reinterpret_cast<const float4*>(emb + (size_t)k * DIM + d);
        e[d] = v.x; e[d + 1] = v.y; e[d + 2] = v.z; e[d + 3] = v.w;
    }
    csum[k] = np_pairwise64_sq(e);
}

// ---- fused: split-K argmin + codes + z_q + loss + LDS histogram ----
__global__ __launch_bounds__(256) void k_scores(
        const float* __restrict__ ze, const float* __restrict__ emb,
        const float* __restrict__ csum, float* __restrict__ out,
        int* __restrict__ codes_i, int* __restrict__ counts,
        double* __restrict__ lossAcc) {
    __shared__ float xs[DIM][128];   // xs[d][c] = 2*x_d for row c of this block
    __shared__ float ms[128];        // hi-half min
    __shared__ int   hi_i[128];      // hi-half argmin
    __shared__ int h[NCODE];
    __shared__ double ls[4];
    int t = threadIdx.x;
    int c = t & 127;                 // row-in-block / xs column
    int half = t >> 7;               // 0: codes 0-255, 1: codes 256-511
    for (int i = t; i < NCODE; i += 256) h[i] = 0;

    int row = blockIdx.x * 128 + c;
    const float* x = ze + (size_t)row * DIM;

    // Both halves load the row (same addresses -> cache hits), both write xs
    // (identical bits -> benign race; each thread reads only its own column).
    float r0, r1, r2, r3, r4, r5, r6, r7;
    {   // d = 0..7: initialize numpy pairwise partials
        float4 va = *reinterpret_cast<const float4*>(x + 0);
        float4 vb = *reinterpret_cast<const float4*>(x + 4);
        float d0 = __fadd_rn(va.x, va.x), d1 = __fadd_rn(va.y, va.y);
        float d2 = __fadd_rn(va.z, va.z), d3 = __fadd_rn(va.w, va.w);
        float d4 = __fadd_rn(vb.x, vb.x), d5 = __fadd_rn(vb.y, vb.y);
        float d6 = __fadd_rn(vb.z, vb.z), d7 = __fadd_rn(vb.w, vb.w);
        xs[0][c] = d0; xs[1][c] = d1; xs[2][c] = d2; xs[3][c] = d3;
        xs[4][c] = d4; xs[5][c] = d5; xs[6][c] = d6; xs[7][c] = d7;
        r0 = __fmul_rn(d0, d0); r1 = __fmul_rn(d1, d1);
        r2 = __fmul_rn(d2, d2); r3 = __fmul_rn(d3, d3);
        r4 = __fmul_rn(d4, d4); r5 = __fmul_rn(d5, d5);
        r6 = __fmul_rn(d6, d6); r7 = __fmul_rn(d7, d7);
    }
#define LD8(b) { \
        float4 va = *reinterpret_cast<const float4*>(x + 8 * (b)); \
        float4 vb = *reinterpret_cast<const float4*>(x + 8 * (b) + 4); \
        float d0 = __fadd_rn(va.x, va.x), d1 = __fadd_rn(va.y, va.y); \
        float d2 = __fadd_rn(va.z, va.z), d3 = __fadd_rn(va.w, va.w); \
        float d4 = __fadd_rn(vb.x, vb.x), d5 = __fadd_rn(vb.y, vb.y); \
        float d6 = __fadd_rn(vb.z, vb.z), d7 = __fadd_rn(vb.w, vb.w); \
        xs[8 * (b) + 0][c] = d0; xs[8 * (b) + 1][c] = d1; \
        xs[8 * (b) + 2][c] = d2; xs[8 * (b) + 3][c] = d3; \
        xs[8 * (b) + 4][c] = d4; xs[8 * (b) + 5][c] = d5; \
        xs[8 * (b) + 6][c] = d6; xs[8 * (b) + 7][c] = d7; \
        r0 = __fadd_rn(r0, __fmul_rn(d0, d0)); r1 = __fadd_rn(r1, __fmul_rn(d1, d1)); \
        r2 = __fadd_rn(r2, __fmul_rn(d2, d2)); r3 = __fadd_rn(r3, __fmul_rn(d3, d3)); \
        r4 = __fadd_rn(r4, __fmul_rn(d4, d4)); r5 = __fadd_rn(r5, __fmul_rn(d5, d5)); \
        r6 = __fadd_rn(r6, __fmul_rn(d6, d6)); r7 = __fadd_rn(r7, __fmul_rn(d7, d7)); }
    LD8(1) LD8(2) LD8(3) LD8(4) LD8(5) LD8(6) LD8(7)
    // A = sum(x^2) = 0.25 * sum((2x)^2), numpy pairwise combine, bit-exact
    float A = __fmul_rn(0.25f,
        __fadd_rn(__fadd_rn(__fadd_rn(r0, r1), __fadd_rn(r2, r3)),
                  __fadd_rn(__fadd_rn(r4, r5), __fadd_rn(r6, r7))));

    // wave-uniform code base; readfirstlane keeps emb loads on the s_load path
    int kbase = __builtin_amdgcn_readfirstlane(half << 8);

    float m1 = 3.4e38f;
    int i1 = kbase;
#define FMAD(dd) { const float xv = xs[dd][c]; \
        a0 = __builtin_fmaf(xv, e[(dd)      ], a0); \
        a1 = __builtin_fmaf(xv, e[(dd) +  64], a1); \
        a2 = __builtin_fmaf(xv, e[(dd) + 128], a2); \
        a3 = __builtin_fmaf(xv, e[(dd) + 192], a3); \
        a4 = __builtin_fmaf(xv, e[(dd) + 256], a4); \
        a5 = __builtin_fmaf(xv, e[(dd) + 320], a5); \
        a6 = __builtin_fmaf(xv, e[(dd) + 384], a6); \
        a7 = __builtin_fmaf(xv, e[(dd) + 448], a7); }
    for (int kk = 0; kk < NCODE / 2; kk += 8) {
        int k = kbase + kk;
        const float* e = emb + (size_t)k * DIM;     // wave-uniform -> scalar loads
        float a0 = 0.f, a1 = 0.f, a2 = 0.f, a3 = 0.f;
        float a4 = 0.f, a5 = 0.f, a6 = 0.f, a7 = 0.f;
        R16(FMAD, 0) R16(FMAD, 16) R16(FMAD, 32) R16(FMAD, 48)   // d ascending, BLAS chain
        float t0 = __fadd_rn(__fsub_rn(A, a0), csum[k + 0]);
        float t1 = __fadd_rn(__fsub_rn(A, a1), csum[k + 1]);
        float t2 = __fadd_rn(__fsub_rn(A, a2), csum[k + 2]);
        float t3 = __fadd_rn(__fsub_rn(A, a3), csum[k + 3]);
        float t4 = __fadd_rn(__fsub_rn(A, a4), csum[k + 4]);
        float t5 = __fadd_rn(__fsub_rn(A, a5), csum[k + 5]);
        float t6 = __fadd_rn(__fsub_rn(A, a6), csum[k + 6]);
        float t7 = __fadd_rn(__fsub_rn(A, a7), csum[k + 7]);
        if (t0 < m1) { m1 = t0; i1 = k; }           // strict < keeps first occurrence
        if (t1 < m1) { m1 = t1; i1 = k + 1; }
        if (t2 < m1) { m1 = t2; i1 = k + 2; }
        if (t3 < m1) { m1 = t3; i1 = k + 3; }
        if (t4 < m1) { m1 = t4; i1 = k + 4; }
        if (t5 < m1) { m1 = t5; i1 = k + 5; }
        if (t6 < m1) { m1 = t6; i1 = k + 6; }
        if (t7 < m1) { m1 = t7; i1 = k + 7; }
    }
    if (half) { ms[c] = m1; hi_i[c] = i1; }
    __syncthreads();                                // hi results + h init visible

    double lsum = 0.0;
    if (!half) {
        float mh = ms[c];
        int ih = hi_i[c];
        if (mh < m1) { m1 = mh; i1 = ih; }          // tie -> lo half = smaller index
        out[OUT_CODES + row] = (float)i1;
        codes_i[row] = i1;
        atomicAdd(&h[i1], 1);                       // LDS atomic

        // z_q = x + (e - x), loss; x recovered exactly as 0.5*(2x)
        const float* e1 = emb + (size_t)i1 * DIM;
        float* zq = out + OUT_ZQ + (size_t)row * DIM;
#define ZQ4(q) { \
        float4 ev = *reinterpret_cast<const float4*>(e1 + 4 * (q)); \
        float xa = __fmul_rn(0.5f, xs[4 * (q) + 0][c]); \
        float xb = __fmul_rn(0.5f, xs[4 * (q) + 1][c]); \
        float xc = __fmul_rn(0.5f, xs[4 * (q) + 2][c]); \
        float xd = __fmul_rn(0.5f, xs[4 * (q) + 3][c]); \
        float ta = __fsub_rn(ev.x, xa); \
        float tb = __fsub_rn(ev.y, xb); \
        float tc = __fsub_rn(ev.z, xc); \
        float td = __fsub_rn(ev.w, xd); \
        float4 o; \
        o.x = __fadd_rn(xa, ta); \
        o.y = __fadd_rn(xb, tb); \
        o.z = __fadd_rn(xc, tc); \
        o.w = __fadd_rn(xd, td); \
        *reinterpret_cast<float4*>(zq + 4 * (q)) = o; \
        lsum += (double)ta * ta + (double)tb * tb + (double)tc * tc + (double)td * td; }
        R16(ZQ4, 0)
    }

    for (int off = 32; off; off >>= 1) lsum += __shfl_down(lsum, off);
    int wid = t >> 6;
    if ((t & 63) == 0) ls[wid] = lsum;              // hi waves contribute 0
    __syncthreads();                                // also orders LDS histogram
    if (t == 0) atomicAdd(lossAcc, (ls[0] + ls[1]) + (ls[2] + ls[3]));
    for (int k = t; k < NCODE; k += 256) {
        int cc = h[k];
        if (cc) atomicAdd(&counts[k], cc);          // int global atomic, aggregated
    }
}

// ---- one block: exclusive scan of counts -> offsets/cursor; new_ecs + n ----
__global__ __launch_bounds__(512) void k_scan(
        const int* __restrict__ counts, int* __restrict__ offsets, int* __restrict__ cursor,
        const float* __restrict__ ecs_in, float* __restrict__ out, float* __restrict__ n_out) {
    __shared__ int sa[NCODE], sb[NCODE];
    __shared__ float red[NCODE];
    int k = threadIdx.x;
    int c = counts[k];
    sa[k] = c;
    float v = __fadd_rn(__fmul_rn(ecs_in[k], DECAY_C), __fmul_rn((float)c, OMD_C));
    out[OUT_ECS + k] = v;
    red[k] = v;
    __syncthreads();
    int* src = sa;
    int* dst = sb;
    for (int off = 1; off < NCODE; off <<= 1) {
        dst[k] = (k >= off) ? src[k - off] + src[k] : src[k];
        __syncthreads();
        int* tp = src; src = dst; dst = tp;
    }
    offsets[k] = src[k] - c;
    cursor[k]  = src[k] - c;
    for (int s = NCODE / 2; s > 0; s >>= 1) {
        if (k < s) red[k] += red[k + s];
        __syncthreads();
    }
    if (k == 0) n_out[0] = red[0];
}

// ---- scatter rows into code buckets ----
__global__ __launch_bounds__(256) void k_scatter(
        const int* __restrict__ codes_i, int* __restrict__ cursor, int* __restrict__ bucket) {
    int row = blockIdx.x * 256 + threadIdx.x;
    int c = codes_i[row];
    int pos = atomicAdd(&cursor[c], 1);
    bucket[pos] = row;
}

// ---- per-code segmented sum, 4 blocks per code -> dw4 partials (no atomics) ----
__global__ __launch_bounds__(256) void k_dw(
        const float* __restrict__ ze, const int* __restrict__ bucket,
        const int* __restrict__ offsets, const int* __restrict__ counts,
        float* __restrict__ dw4) {
    __shared__ float p[4][DIM];
    int k = blockIdx.x >> 2;
    int q = blockIdx.x & 3;         // quarter of this bucket
    int w = threadIdx.x >> 6;       // wave 0..3
    int d = threadIdx.x & 63;
    int s = offsets[k];
    int n = counts[k];
    float acc0 = 0.f, acc1 = 0.f;
    int i = q + 4 * w;              // residue q mod 4, wave-strided
    for (; i + 16 < n; i += 32) {   // 2 gathers in flight per wave
        int ra = bucket[s + i];
        int rb = bucket[s + i + 16];
        acc0 += ze[(size_t)ra * DIM + d];
        acc1 += ze[(size_t)rb * DIM + d];
    }
    if (i < n) acc0 += ze[(size_t)bucket[s + i] * DIM + d];
    p[w][d] = acc0 + acc1;
    __syncthreads();
    if (w == 0) dw4[((size_t)q * NCODE + k) * DIM + d] = (p[0][d] + p[1][d]) + (p[2][d] + p[3][d]);
}

// ---- new_ema_w, new_emb, loss ----
__global__ __launch_bounds__(256) void k_final(
        const float* __restrict__ ema_w, const float* __restrict__ dw4,
        const float* __restrict__ n_ptr, const double* __restrict__ lossAcc,
        float* __restrict__ out) {
    int i = blockIdx.x * blockDim.x + threadIdx.x;
    if (i >= NCODE * DIM) return;
    int k = i >> 6;
    float dsum = __fadd_rn(__fadd_rn(dw4[i], dw4[i + NCODE * DIM]),
                           __fadd_rn(dw4[i + 2 * NCODE * DIM], dw4[i + 3 * NCODE * DIM]));
    float w = __fadd_rn(__fmul_rn(ema_w[i], DECAY_C), __fmul_rn(dsum, OMD_C));
    out[OUT_EMAW + i] = w;
    float n = n_ptr[0];
    float necs = out[OUT_ECS + k];
    float cs = (necs + EPS_C) / (n + (float)NCODE * EPS_C) * n;
    out[OUT_EMB + i] = w / (cs + EPS_C);
    if (i == 0) out[OUT_LOSS] = (float)(0.1 * (lossAcc[0] / (double)((size_t)NROWS * DIM)));
}

extern "C" void kernel_launch(void* const* d_in, const int* in_sizes, int n_in,
                              void* d_out, int out_size, void* d_ws, size_t ws_size,
                              hipStream_t stream) {
    const float* ze   = (const float*)d_in[0];
    const float* emb  = (const float*)d_in[1];
    const float* ecs  = (const float*)d_in[2];
    const float* emaw = (const float*)d_in[3];
    float* out = (float*)d_out;
    char* ws = (char*)d_ws;
    double* lossAcc = (double*)(ws + WS_LOSS);
    float*  n_out   = (float*)(ws + WS_N);
    int*    counts  = (int*)(ws + WS_COUNTS);
    int*    offsets = (int*)(ws + WS_OFFSETS);
    int*    cursor  = (int*)(ws + WS_CURSOR);
    float*  csum    = (float*)(ws + WS_CSUM);
    int*    codes_i = (int*)(ws + WS_CODESI);
    float*  dw4     = (float*)(ws + WS_DW4);     // aliases codes_i (k_dw after k_scatter)
    int*    bucket  = (int*)(ws + WS_BUCKET);

    hipMemsetAsync(d_ws, 0, WS_ZERO_BYTES, stream);
    hipLaunchKernelGGL(k_csum, dim3(2), dim3(256), 0, stream, emb, csum);
    hipLaunchKernelGGL(k_scores, dim3(NROWS / 128), dim3(256), 0, stream,
                       ze, emb, csum, out, codes_i, counts, lossAcc);
    hipLaunchKernelGGL(k_scan, dim3(1), dim3(512), 0, stream,
                       counts, offsets, cursor, ecs, out, n_out);
    hipLaunchKernelGGL(k_scatter, dim3(NROWS / 256), dim3(256), 0, stream,
                       codes_i, cursor, bucket);
    hipLaunchKernelGGL(k_dw, dim3(NCODE * 4), dim3(256), 0, stream,
                       ze, bucket, offsets, counts, dw4);
    hipLaunchKernelGGL(k_final, dim3(NCODE * DIM / 256), dim3(256), 0, stream,
                       emaw, dw4, n_out, lossAcc, out);
}